// Round 9
// baseline (503.036 us; speedup 1.0000x reference)
//
#include <hip/hip_runtime.h>

// ---------- types / helpers ----------
typedef __attribute__((ext_vector_type(8))) short bf16x8;    // 8 bf16 (4 VGPRs)
typedef __attribute__((ext_vector_type(16))) float f32x16;   // 32x32 MFMA acc

__device__ __forceinline__ unsigned short f2bf(float f) {
    union { float f; unsigned int u; } v; v.f = f;
    unsigned int u = v.u;
    unsigned int r = (u + 0x7FFFu + ((u >> 16) & 1u)) >> 16;   // RNE
    return (unsigned short)r;
}
__device__ __forceinline__ float bf2f(unsigned short b) {
    union { unsigned int u; float f; } v; v.u = ((unsigned int)b) << 16;
    return v.f;
}

#define GL16(g, l)                                                             \
    __builtin_amdgcn_global_load_lds(                                          \
        (__attribute__((address_space(1))) void*)(void*)(g),                   \
        (__attribute__((address_space(3))) void*)(void*)(l), 16, 0, 0)

#define BAR()   __builtin_amdgcn_s_barrier()
#define LGKM0() asm volatile("s_waitcnt lgkmcnt(0)" ::: "memory")

// ---------- merged f32 -> bf16 casts (one launch, 5 segments) ----------
struct Cast5 {
    const float *s0, *s1, *s2, *s3, *s4;
    unsigned short *d0, *d1, *d2, *d3, *d4;
    int n0, n1, n2, n3, total;
};
__global__ void castall(Cast5 a) {
    int stride = gridDim.x * blockDim.x;
    for (int i = blockIdx.x * blockDim.x + threadIdx.x; i < a.total; i += stride) {
        int j = i; const float* s; unsigned short* d;
        if (j < a.n0) { s = a.s0; d = a.d0; }
        else { j -= a.n0;
            if (j < a.n1) { s = a.s1; d = a.d1; }
            else { j -= a.n1;
                if (j < a.n2) { s = a.s2; d = a.d2; }
                else { j -= a.n2;
                    if (j < a.n3) { s = a.s3; d = a.d3; }
                    else { j -= a.n3; s = a.s4; d = a.d4; } } } }
        float4 v = ((const float4*)s)[j];
        ushort4 o;
        o.x = f2bf(v.x); o.y = f2bf(v.y); o.z = f2bf(v.z); o.w = f2bf(v.w);
        ((ushort4*)d)[j] = o;
    }
}

// ---------- 8-phase (MP*64 x 256) NT GEMM, 32x32x16 MFMA, chunked LDS ----------
// R6 schedule: read-ahead one phase, 1 barrier/phase, vmcnt(6/5) at P2/P4,
// compile-time buffer parity (K-loop x2).
// LDS layout per half-tile (ROWS x 64k): chunk c (16B) = ksub*ROWS + row,
// ksub = k-halfslice 0..7 (8 bf16 each). Reads: 32 lanes x consecutive rows
// -> contiguous 512B, conflict-free. Staging: linear LDS dest (global_load_lds),
// per-lane global source offset (row%ROWS)*K*2 + (c/ROWS)*16 (pre-swizzled src).
// Fragments 32x32x16 bf16: A/B row=lane&31, k-half=(lane>>5) [HW-verified R8];
// C/D col=lane&31, row=(reg&3)+8*(reg>>2)+4*(lane>>5) [m74/m101].

template<int RELU, int OUT_BF16, int MP>
__global__ __launch_bounds__(512, 2) void gemm8p(
    const unsigned short* __restrict__ A,   // M x K bf16
    const unsigned short* __restrict__ Bm,  // N x K bf16
    const float* __restrict__ bias,         // N
    void* __restrict__ Cout,                // M x N
    int N, int K, int NT)
{
    constexpr int RT   = MP / 2;            // 32-row tiles per quadrant
    constexpr int ARWS = MP * 32;           // rows per A half
    constexpr int ASH  = (MP == 4) ? 7 : 6; // log2(ARWS)
    constexpr int AHB  = MP * 4096;         // bytes per A half
    constexpr int BOFFB = 4 * AHB;          // byte offset of B region
    __shared__ __align__(16) unsigned short lds[MP * 8192 + 32768];
    char* ldsc = (char*)lds;

    const int tid  = threadIdx.x;
    const int lane = tid & 63;
    const int w    = tid >> 6;
    const int wm   = w >> 2;           // 0..1
    const int wn   = w & 3;            // 0..3
    const int bm   = blockIdx.y;
    const int bn   = blockIdx.x;

    // ---- block panel bases (uniform -> SGPR) ----
    const unsigned short* gA = A  + (long)bm * (MP * 64) * K;
    const unsigned short* gB = Bm + (long)bn * 256 * K;

    // ---- staging: per-lane global byte offsets (chunk c = tid, pass2 = +64B) ----
    const int loffA = (tid & (ARWS - 1)) * (K * 2) + (tid >> ASH) * 16;
    const int loffB = (tid & 127) * (K * 2) + (tid >> 7) * 16;
    const int lwb   = w * 1024;              // wave-uniform LDS byte base

    // ---- LDS read bases (per-lane, byte) ----
    const int l31  = lane & 31;
    const int hi   = lane >> 5;               // k-half select
    const int aBase = wm * (MP * 256) + l31 * 16 + hi * (ARWS * 16);
    const int bBase = BOFFB + wn * 512 + l31 * 16 + hi * 2048;

    f32x16 acc[2][2][RT] = {};
    bf16x8 a0[RT][4], a1[RT][4], b0[4], b1[4];

#define GLA_(SP, DI) do {                                                      \
        GL16((const char*)(SP) + loffA, ldsc + (DI) + lwb);                    \
        if constexpr (MP == 4) {                                               \
            GL16((const char*)(SP) + loffA + 64, ldsc + (DI) + 8192 + lwb); }  \
    } while (0)
#define GLB_(SP, DI) do {                                                      \
        GL16((const char*)(SP) + loffB, ldsc + (DI) + lwb);                    \
        GL16((const char*)(SP) + loffB + 64, ldsc + (DI) + 8192 + lwb);        \
    } while (0)

#define READA_(AR, MH, PAR) do {                                               \
        _Pragma("unroll") for (int rt_ = 0; rt_ < RT; ++rt_)                   \
        _Pragma("unroll") for (int ks_ = 0; ks_ < 4; ++ks_)                    \
            AR[rt_][ks_] = *(const bf16x8*)(ldsc + aBase +                     \
                (((PAR)*2+(MH))*AHB + rt_*512 + ks_*(ARWS*32)));               \
    } while (0)
#define READB_(BR, NH, PAR) do {                                               \
        _Pragma("unroll") for (int ks_ = 0; ks_ < 4; ++ks_)                    \
            BR[ks_] = *(const bf16x8*)(ldsc + bBase +                          \
                (((PAR)*2+(NH))*16384 + ks_*4096));                            \
    } while (0)
#define QUAD(mh, nh, AR, BR) do {                                              \
        __builtin_amdgcn_s_setprio(1);                                         \
        _Pragma("unroll") for (int ks_ = 0; ks_ < 4; ++ks_)                    \
        _Pragma("unroll") for (int rt_ = 0; rt_ < RT; ++rt_)                   \
            acc[mh][nh][rt_] = __builtin_amdgcn_mfma_f32_32x32x16_bf16(        \
                AR[rt_][ks_], BR[ks_], acc[mh][nh][rt_], 0, 0, 0);             \
        __builtin_amdgcn_s_setprio(0);                                         \
    } while (0)
#define VMW() do {                                                             \
        if constexpr (MP == 4) asm volatile("s_waitcnt vmcnt(6)" ::: "memory");\
        else                   asm volatile("s_waitcnt vmcnt(5)" ::: "memory");\
    } while (0)

    // ---- prologue: tile0 {B0,A0,B1,A1} + tile1 {B0,A0,B1} (op order = ledger) ----
    GLB_(gB,                      BOFFB + 0);
    GLA_(gA,                      0);
    GLB_(gB + (long)128 * K,      BOFFB + 16384);
    GLA_(gA + (long)(MP*32) * K,  AHB);
    GLB_(gB + 64,                 BOFFB + 2*16384);
    GLA_(gA + 64,                 2*AHB);
    GLB_(gB + (long)128 * K + 64, BOFFB + 3*16384);
    VMW();
    BAR();
    READA_(a0, 0, 0);
    READB_(b0, 0, 0);

    // ---- running scalar column pointers ----
    const unsigned short* sA1 = gA + (long)(MP*32) * K + 64;   // col 1
    const unsigned short* sA0 = gA + 128;                      // col 2
    const unsigned short* sB0 = gB + 128;                      // col 2
    const unsigned short* sB1 = gB + (long)128 * K + 128;      // col 2

#define KTILE(T, PAR) do {                                                     \
        const int adv1_ = ((T) + 2 < NT) ? 64 : 0;                             \
        const int adv2_ = ((T) + 3 < NT) ? 64 : 0;                             \
        /* P1 */                                                               \
        READA_(a1, 1, PAR);                                                    \
        GLA_(sA1, (((PAR)^1)*2+1)*AHB); sA1 += adv1_;                          \
        BAR();                                                                 \
        QUAD(0, 0, a0, b0);                                                    \
        /* P2 */                                                               \
        READB_(b1, 1, PAR);                                                    \
        GLB_(sB0, BOFFB + (PAR)*2*16384); sB0 += adv2_;                        \
        VMW();                                                                 \
        BAR();                                                                 \
        QUAD(0, 1, a0, b1);                                                    \
        /* P3 */                                                               \
        READA_(a0, 0, (PAR)^1);                                                \
        GLA_(sA0, (PAR)*2*AHB); sA0 += adv2_;                                  \
        BAR();                                                                 \
        QUAD(1, 1, a1, b1);                                                    \
        /* P4 */                                                               \
        GLB_(sB1, BOFFB + ((PAR)*2+1)*16384); sB1 += adv2_;                    \
        VMW();                                                                 \
        BAR();                                                                 \
        QUAD(1, 0, a1, b0);                                                    \
        READB_(b0, 0, (PAR)^1);                                                \
    } while (0)

    for (int t = 0; t < NT; t += 2) {
        KTILE(t, 0);
        KTILE(t + 1, 1);
    }

    // drain clamped wrap-stagings before LDS reuse / kernel end
    asm volatile("s_waitcnt vmcnt(0)" ::: "memory");
    BAR();

    // ---- epilogue: C/D col=lane&31, row=(reg&3)+8*(reg>>2)+4*(lane>>5) ----
    const int rbase = hi * 4;
    float bv[2];
    #pragma unroll
    for (int nh = 0; nh < 2; ++nh)
        bv[nh] = bias[(long)bn * 256 + nh * 128 + wn * 32 + l31];

    if (OUT_BF16) {
        unsigned short* epi = lds;
        #pragma unroll
        for (int h = 0; h < 2; ++h) {
            if (h) { LGKM0(); BAR(); }
            #pragma unroll
            for (int rt = 0; rt < RT; ++rt)
                #pragma unroll
                for (int nh = 0; nh < 2; ++nh) {
                    int lcol = nh * 128 + wn * 32 + l31;
                    #pragma unroll
                    for (int reg = 0; reg < 16; ++reg) {
                        float v = acc[h][nh][rt][reg] + bv[nh];
                        if (RELU) v = fmaxf(v, 0.f);
                        int lrow = wm * (MP * 16) + rt * 32 +
                                   (reg & 3) + ((reg >> 2) << 3) + rbase;
                        epi[lrow * 264 + lcol] = f2bf(v);
                    }
                }
            LGKM0();
            BAR();
            long rowg0 = (long)bm * (MP * 64) + h * (MP * 32);
            #pragma unroll
            for (int i = 0; i < 2 * MP; ++i) {
                int row = (tid >> 5) + i * 16;
                int cc  = (tid & 31) * 8;
                bf16x8 v8 = *(const bf16x8*)&epi[row * 264 + cc];
                *(bf16x8*)((unsigned short*)Cout + (rowg0 + row) * (long)N + (long)bn * 256 + cc) = v8;
            }
        }
    } else {
        #pragma unroll
        for (int mh = 0; mh < 2; ++mh)
            #pragma unroll
            for (int rt = 0; rt < RT; ++rt)
                #pragma unroll
                for (int nh = 0; nh < 2; ++nh) {
                    long gcol = (long)bn * 256 + nh * 128 + wn * 32 + l31;
                    long growb = (long)bm * (MP * 64) + mh * (MP * 32) +
                                 wm * (MP * 16) + rt * 32 + rbase;
                    #pragma unroll
                    for (int reg = 0; reg < 16; ++reg) {
                        float v = acc[mh][nh][rt][reg] + bv[nh];
                        if (RELU) v = fmaxf(v, 0.f);
                        long grow = growb + (reg & 3) + ((reg >> 2) << 3);
                        ((float*)Cout)[grow * (long)N + gcol] = v;
                    }
                }
    }
#undef GLA_
#undef GLB_
#undef READA_
#undef READB_
#undef QUAD
#undef VMW
#undef KTILE
}

// ---------- fused: latent(16) -> quantum circuit -> D1 ----------
__global__ __launch_bounds__(256) void latq_d1(
    const unsigned short* __restrict__ h2,  // B x 1024 bf16
    const float* __restrict__ We3,          // 256 x 1024 (rows 0..15 used)
    const float* __restrict__ be3,          // 256
    const float* __restrict__ P,            // 2 x 16 x 3
    const float* __restrict__ Wd1,          // 1024 x 16
    const float* __restrict__ bd1,          // 1024
    unsigned short* __restrict__ h3)        // B x 1024 bf16
{
    __shared__ float zsh[4][16];
    const int lane = threadIdx.x & 63;
    const int wv   = threadIdx.x >> 6;
    const long row = (long)blockIdx.x * 4 + wv;

    float hreg[16];
    const unsigned short* hr = h2 + row * 1024;
    #pragma unroll
    for (int j = 0; j < 16; ++j) hreg[j] = bf2f(hr[lane + 64 * j]);

    float myth = 0.f;
    #pragma unroll
    for (int q = 0; q < 16; ++q) {
        const float* wq = We3 + q * 1024;
        float p = 0.f;
        #pragma unroll
        for (int j = 0; j < 16; ++j) p += hreg[j] * wq[lane + 64 * j];
        #pragma unroll
        for (int o = 32; o; o >>= 1) p += __shfl_xor(p, o, 64);
        if (lane == q) myth = p + be3[q];
    }

    if (lane < 16) {
        const int q = lane;
        float ar = cosf(0.5f * myth), ai = 0.f;
        float br = sinf(0.5f * myth), bi = 0.f;
        #pragma unroll
        for (int l = 0; l < 2; ++l) {
            const float* pp = P + (l * 16 + q) * 3;
            float t, c, s, ar2, ai2, br2, bi2;
            t = 0.5f * pp[0]; c = cosf(t); s = sinf(t);
            ar2 = c * ar + s * bi;  ai2 = c * ai - s * br;
            br2 = c * br + s * ai;  bi2 = c * bi - s * ar;
            ar = ar2; ai = ai2; br = br2; bi = bi2;
            t = 0.5f * pp[1]; c = cosf(t); s = sinf(t);
            ar2 = c * ar - s * br;  ai2 = c * ai - s * bi;
            br2 = s * ar + c * br;  bi2 = s * ai + c * bi;
            ar = ar2; ai = ai2; br = br2; bi = bi2;
            t = 0.5f * pp[2]; c = cosf(t); s = sinf(t);
            ar2 = ar * c + ai * s;  ai2 = ai * c - ar * s;
            br2 = br * c - bi * s;  bi2 = bi * c + br * s;
            ar = ar2; ai = ai2; br = br2; bi = bi2;
        }
        zsh[wv][q] = ar * ar + ai * ai - (br * br + bi * bi);
    }
    __syncthreads();

    float z[16];
    #pragma unroll
    for (int q = 0; q < 16; ++q) z[q] = zsh[wv][q];

    unsigned short* orow = h3 + row * 1024;
    #pragma unroll
    for (int i = 0; i < 16; ++i) {
        int j = lane + 64 * i;
        const float4* wrow = (const float4*)(Wd1 + j * 16);
        float acc = bd1[j];
        #pragma unroll
        for (int qq = 0; qq < 4; ++qq) {
            float4 w4 = wrow[qq];
            acc += z[qq * 4 + 0] * w4.x + z[qq * 4 + 1] * w4.y
                 + z[qq * 4 + 2] * w4.z + z[qq * 4 + 3] * w4.w;
        }
        orow[j] = f2bf(fmaxf(acc, 0.f));
    }
}

// ---------- host ----------
extern "C" void kernel_launch(void* const* d_in, const int* in_sizes, int n_in,
                              void* d_out, int out_size, void* d_ws, size_t ws_size,
                              hipStream_t stream) {
    const float* x   = (const float*)d_in[0];
    const float* We1 = (const float*)d_in[1];
    const float* be1 = (const float*)d_in[2];
    const float* We2 = (const float*)d_in[3];
    const float* be2 = (const float*)d_in[4];
    const float* We3 = (const float*)d_in[5];
    const float* be3 = (const float*)d_in[6];
    const float* P   = (const float*)d_in[7];
    const float* Wd1 = (const float*)d_in[8];
    const float* bd1 = (const float*)d_in[9];
    const float* Wd2 = (const float*)d_in[10];
    const float* bd2 = (const float*)d_in[11];
    const float* Wd3 = (const float*)d_in[12];
    const float* bd3 = (const float*)d_in[13];

    const int B = 8192, DIN = 4096, NH1 = 2048, NH2 = 1024;

    char* w = (char*)d_ws;
    unsigned short* x_bf   = (unsigned short*)(w);                    // 64MB
    unsigned short* h4     = x_bf;                                    // alias (x dead after G1)
    unsigned short* We1_bf = (unsigned short*)(w + 67108864L);        // 16MB
    unsigned short* We2_bf = (unsigned short*)(w + 83886080L);        // 4MB
    unsigned short* Wd2_bf = (unsigned short*)(w + 88080384L);        // 4MB
    unsigned short* Wd3_bf = (unsigned short*)(w + 92274688L);        // 16MB
    unsigned short* h1     = (unsigned short*)(w + 109051904L);       // 32MB
    unsigned short* h3     = h1;                                      // alias (h1 dead after G2)
    unsigned short* h2     = (unsigned short*)(w + 142606336L);       // 16MB

    Cast5 ca;
    ca.s0 = x;   ca.d0 = x_bf;   ca.n0 = (int)((long)B * DIN / 4);
    ca.s1 = We1; ca.d1 = We1_bf; ca.n1 = (int)((long)NH1 * DIN / 4);
    ca.s2 = We2; ca.d2 = We2_bf; ca.n2 = (int)((long)NH2 * NH1 / 4);
    ca.s3 = Wd2; ca.d3 = Wd2_bf; ca.n3 = (int)((long)NH1 * NH2 / 4);
    ca.s4 = Wd3; ca.d4 = Wd3_bf;
    ca.total = ca.n0 + ca.n1 + ca.n2 + ca.n3 + (int)((long)DIN * NH1 / 4);
    castall<<<2048, 256, 0, stream>>>(ca);

    // G1: h1 = relu(x @ We1^T + be1)   8192x2048 K=4096   (256x256)
    gemm8p<1, 1, 4><<<dim3(NH1 / 256, B / 256), 512, 0, stream>>>(x_bf, We1_bf, be1, h1, NH1, DIN, DIN >> 6);
    // G2: h2 = relu(h1 @ We2^T + be2)  8192x1024 K=2048   (128x256)
    gemm8p<1, 1, 2><<<dim3(NH2 / 256, B / 128), 512, 0, stream>>>(h1, We2_bf, be2, h2, NH2, NH1, NH1 >> 6);
    // latent -> quantum -> D1
    latq_d1<<<dim3(B / 4), 256, 0, stream>>>(h2, We3, be3, P, Wd1, bd1, h3);
    // D2: h4 = relu(h3 @ Wd2^T + bd2)  8192x2048 K=1024   (256x256)
    gemm8p<1, 1, 4><<<dim3(NH1 / 256, B / 256), 512, 0, stream>>>(h3, Wd2_bf, bd2, h4, NH1, NH2, NH2 >> 6);
    // D3: out = h4 @ Wd3^T + bd3       8192x4096 K=2048 -> f32
    gemm8p<0, 0, 4><<<dim3(DIN / 256, B / 256), 512, 0, stream>>>(h4, Wd3_bf, bd3, d_out, DIN, NH1, NH1 >> 6);
}

// Round 10
// 381.077 us; speedup vs baseline: 1.3200x; 1.3200x over previous
//
#include <hip/hip_runtime.h>

// ---------- types / helpers ----------
typedef __attribute__((ext_vector_type(8))) short bf16x8;  // 8 bf16 (4 VGPRs)
typedef __attribute__((ext_vector_type(4))) float f32x4;

__device__ __forceinline__ unsigned short f2bf(float f) {
    union { float f; unsigned int u; } v; v.f = f;
    unsigned int u = v.u;
    unsigned int r = (u + 0x7FFFu + ((u >> 16) & 1u)) >> 16;   // RNE
    return (unsigned short)r;
}
__device__ __forceinline__ float bf2f(unsigned short b) {
    union { unsigned int u; float f; } v; v.u = ((unsigned int)b) << 16;
    return v.f;
}

#define GL16(g, l)                                                             \
    __builtin_amdgcn_global_load_lds(                                          \
        (__attribute__((address_space(1))) void*)(void*)(g),                   \
        (__attribute__((address_space(3))) void*)(void*)(l), 16, 0, 0)

#define BAR()   __builtin_amdgcn_s_barrier()
#define LGKM0() asm volatile("s_waitcnt lgkmcnt(0)" ::: "memory")

// ---------- merged f32 -> bf16 casts (one launch, 5 segments) ----------
struct Cast5 {
    const float *s0, *s1, *s2, *s3, *s4;
    unsigned short *d0, *d1, *d2, *d3, *d4;
    int n0, n1, n2, n3, total;
};
__global__ void castall(Cast5 a) {
    int stride = gridDim.x * blockDim.x;
    for (int i = blockIdx.x * blockDim.x + threadIdx.x; i < a.total; i += stride) {
        int j = i; const float* s; unsigned short* d;
        if (j < a.n0) { s = a.s0; d = a.d0; }
        else { j -= a.n0;
            if (j < a.n1) { s = a.s1; d = a.d1; }
            else { j -= a.n1;
                if (j < a.n2) { s = a.s2; d = a.d2; }
                else { j -= a.n2;
                    if (j < a.n3) { s = a.s3; d = a.d3; }
                    else { j -= a.n3; s = a.s4; d = a.d4; } } } }
        float4 v = ((const float4*)s)[j];
        ushort4 o;
        o.x = f2bf(v.x); o.y = f2bf(v.y); o.z = f2bf(v.z); o.w = f2bf(v.w);
        ((ushort4*)d)[j] = o;
    }
}

// ---------- 8-phase (MP*64 x 256) NT GEMM, 2 barriers/K-tile ----------
// R6 base (best measured, 388.6us): read-ahead one phase, compile-time buffer
// parity (K-loop x2), vmcnt(6/5) at P2/P4. THIS ROUND: barriers only after the
// two VMWs (P2,P4) -- P1/P3 barriers deleted so waves drift up to 2 phases and
// LDS-read windows overlap other waves' MFMA windows (the two ~55%-of-wall
// pipes were barrier-serialized). Ledger audit (MP=4, 2 ops/stage):
//  read a1(t)@P1    <- staged t-1.P1, covered by t-1.P4 VMW(6)+BAR
//  read b1(t)@P2    <- staged t-2.P4, older ✓ (same VMW)
//  read a0(t+1)@P3  <- staged t-1.P3, covered by t.P2 VMW(6)+BAR
//  read b0(t+1)@P4  <- staged t-1.P2, older ✓ (same VMW)
// WAR: every overwrite lands >=1 VMW+BAR after its readers' lgkm-consumption.

template<int RELU, int OUT_BF16, int MP>
__global__ __launch_bounds__(512, 2) void gemm8p(
    const unsigned short* __restrict__ A,   // M x K bf16
    const unsigned short* __restrict__ Bm,  // N x K bf16
    const float* __restrict__ bias,         // N
    void* __restrict__ Cout,                // M x N
    int N, int K, int NT)
{
    constexpr int AHU  = MP * 2048;       // ushorts per A half (MP*32 rows x 64)
    constexpr int BOFF = MP * 8192;       // ushort offset of B region
    __shared__ __align__(16) unsigned short lds[MP * 8192 + 32768];

    const int tid  = threadIdx.x;
    const int lane = tid & 63;
    const int w    = tid >> 6;
    const int wm   = w >> 2;           // 0..1
    const int wn   = w & 3;            // 0..3
    const int bm   = blockIdx.y;
    const int bn   = blockIdx.x;

    // ---- block panel bases (uniform -> SGPR) ----
    const unsigned short* gA = A  + (long)bm * (MP * 64) * K;
    const unsigned short* gB = Bm + (long)bn * 256 * K;

    // ---- staging: per-lane byte offset within a half-panel ----
    const int sr0 = tid >> 3;                                      // row 0..63
    const int so0 = (((tid & 7) * 16) ^ ((sr0 & 7) << 4)) >> 1;    // swizzled col (ushort)
    const int loff = (sr0 * K + so0) * 2;                          // bytes
    const int ch1  = K * 128;                                      // +64 rows, bytes
    const int lb0 = (w * 64) * 8;            // wave-uniform LDS chunk base (ushort idx)
    const int lb1 = (512 + w * 64) * 8;

    // ---- LDS read bases (per-lane VGPR, byte) ----
    const int cl  = lane & 15;
    const int g16 = (lane >> 4) * 16;
    const int sw  = (cl & 7) << 4;
    const int cK0 = (g16 ^ sw) >> 1;
    const int cK1 = ((64 + g16) ^ sw) >> 1;
    const int arb = wm * (MP * 16) + cl;
    const int brb = wn * 32 + cl;
    const int aIdx0 = (arb * 64 + cK0) * 2;
    const int aIdx1 = (arb * 64 + cK1) * 2;
    const int bIdx0 = (BOFF + brb * 64 + cK0) * 2;
    const int bIdx1 = (BOFF + brb * 64 + cK1) * 2;

    f32x4  acc[2][2][MP][2] = {};
    bf16x8 a0[MP][2], a1[MP][2], b0[2][2], b1[2][2];

#define GLA_(SP, DI) do {                                                      \
        GL16((const char*)(SP) + loff, &lds[0] + (DI) + lb0);                  \
        if constexpr (MP == 4) {                                               \
            GL16((const char*)(SP) + loff + ch1, &lds[0] + (DI) + lb1); }      \
    } while (0)
#define GLB_(SP, DI) do {                                                      \
        GL16((const char*)(SP) + loff, &lds[0] + (DI) + lb0);                  \
        GL16((const char*)(SP) + loff + ch1, &lds[0] + (DI) + lb1);            \
    } while (0)

#define READA_(AR, MH, PAR) do {                                               \
        _Pragma("unroll") for (int mp_ = 0; mp_ < MP; ++mp_) {                 \
            AR[mp_][0] = *(const bf16x8*)((const char*)lds + aIdx0 +           \
                         (((PAR)*2+(MH))*AHU*2 + mp_*2048));                   \
            AR[mp_][1] = *(const bf16x8*)((const char*)lds + aIdx1 +           \
                         (((PAR)*2+(MH))*AHU*2 + mp_*2048));                   \
        } } while (0)
#define READB_(BR, NH, PAR) do {                                               \
        _Pragma("unroll") for (int np_ = 0; np_ < 2; ++np_) {                  \
            BR[np_][0] = *(const bf16x8*)((const char*)lds + bIdx0 +           \
                         (((PAR)*2+(NH))*16384 + np_*2048));                   \
            BR[np_][1] = *(const bf16x8*)((const char*)lds + bIdx1 +           \
                         (((PAR)*2+(NH))*16384 + np_*2048));                   \
        } } while (0)
#define QUAD(mh, nh, AR, BR) do {                                              \
        __builtin_amdgcn_s_setprio(1);                                         \
        _Pragma("unroll") for (int kk_ = 0; kk_ < 2; ++kk_)                    \
        _Pragma("unroll") for (int mp_ = 0; mp_ < MP; ++mp_)                   \
        _Pragma("unroll") for (int np_ = 0; np_ < 2; ++np_)                    \
            acc[mh][nh][mp_][np_] = __builtin_amdgcn_mfma_f32_16x16x32_bf16(   \
                AR[mp_][kk_], BR[np_][kk_], acc[mh][nh][mp_][np_], 0, 0, 0);   \
        __builtin_amdgcn_s_setprio(0);                                         \
    } while (0)
#define VMW() do {                                                             \
        if constexpr (MP == 4) asm volatile("s_waitcnt vmcnt(6)" ::: "memory");\
        else                   asm volatile("s_waitcnt vmcnt(5)" ::: "memory");\
    } while (0)

    // ---- prologue: tile0 {B0,A0,B1,A1} + tile1 {B0,A0,B1} (this op order!) ----
    GLB_(gB,                      BOFF + 0);
    GLA_(gA,                      0);
    GLB_(gB + (long)128 * K,      BOFF + 8192);
    GLA_(gA + (long)(MP*32) * K,  AHU);
    GLB_(gB + 64,                 BOFF + 2*8192);
    GLA_(gA + 64,                 2*AHU);
    GLB_(gB + (long)128 * K + 64, BOFF + 3*8192);
    VMW();
    BAR();
    READA_(a0, 0, 0);
    READB_(b0, 0, 0);

    // ---- running scalar column pointers ----
    const unsigned short* sA1 = gA + (long)(MP*32) * K + 64;   // col 1
    const unsigned short* sA0 = gA + 128;                      // col 2
    const unsigned short* sB0 = gB + 128;                      // col 2
    const unsigned short* sB1 = gB + (long)128 * K + 128;      // col 2

#define KTILE(T, PAR) do {                                                     \
        const int adv1_ = ((T) + 2 < NT) ? 64 : 0;                             \
        const int adv2_ = ((T) + 3 < NT) ? 64 : 0;                             \
        /* P1 (no barrier) */                                                  \
        READA_(a1, 1, PAR);                                                    \
        GLA_(sA1, (((PAR)^1)*2+1)*AHU); sA1 += adv1_;                          \
        QUAD(0, 0, a0, b0);                                                    \
        /* P2 */                                                               \
        READB_(b1, 1, PAR);                                                    \
        GLB_(sB0, BOFF + (PAR)*2*8192); sB0 += adv2_;                          \
        VMW();                                                                 \
        BAR();                                                                 \
        QUAD(0, 1, a0, b1);                                                    \
        /* P3 (no barrier) */                                                  \
        READA_(a0, 0, (PAR)^1);                                                \
        GLA_(sA0, (PAR)*2*AHU); sA0 += adv2_;                                  \
        QUAD(1, 1, a1, b1);                                                    \
        /* P4 */                                                               \
        GLB_(sB1, BOFF + ((PAR)*2+1)*8192); sB1 += adv2_;                      \
        VMW();                                                                 \
        BAR();                                                                 \
        QUAD(1, 0, a1, b0);                                                    \
        READB_(b0, 0, (PAR)^1);                                                \
    } while (0)

    for (int t = 0; t < NT; t += 2) {
        KTILE(t, 0);
        KTILE(t + 1, 1);
    }

    // drain clamped wrap-stagings before LDS reuse / kernel end
    asm volatile("s_waitcnt vmcnt(0)" ::: "memory");
    BAR();

    // ---- epilogue ----
    const int r4 = (lane >> 4) * 4;
    float bv[2][2];
    #pragma unroll
    for (int nh = 0; nh < 2; ++nh)
        #pragma unroll
        for (int np = 0; np < 2; ++np)
            bv[nh][np] = bias[(long)bn * 256 + nh * 128 + wn * 32 + np * 16 + cl];

    if (OUT_BF16) {
        unsigned short* epi = lds;
        #pragma unroll
        for (int h = 0; h < 2; ++h) {
            if (h) { LGKM0(); BAR(); }
            #pragma unroll
            for (int mp = 0; mp < MP; ++mp)
                #pragma unroll
                for (int nh = 0; nh < 2; ++nh)
                    #pragma unroll
                    for (int np = 0; np < 2; ++np)
                        #pragma unroll
                        for (int r = 0; r < 4; ++r) {
                            float v = acc[h][nh][mp][np][r] + bv[nh][np];
                            if (RELU) v = fmaxf(v, 0.f);
                            int lrow = wm * (MP * 16) + mp * 16 + r4 + r;
                            int lcol = nh * 128 + wn * 32 + np * 16 + cl;
                            epi[lrow * 264 + lcol] = f2bf(v);
                        }
            LGKM0();
            BAR();
            long rowg0 = (long)bm * (MP * 64) + h * (MP * 32);
            #pragma unroll
            for (int i = 0; i < 2 * MP; ++i) {
                int row = (tid >> 5) + i * 16;
                int cc  = (tid & 31) * 8;
                bf16x8 v8 = *(const bf16x8*)&epi[row * 264 + cc];
                *(bf16x8*)((unsigned short*)Cout + (rowg0 + row) * (long)N + (long)bn * 256 + cc) = v8;
            }
        }
    } else {
        #pragma unroll
        for (int mh = 0; mh < 2; ++mh)
            #pragma unroll
            for (int mp = 0; mp < MP; ++mp) {
                long grow = (long)bm * (MP * 64) + mh * (MP * 32) + wm * (MP * 16) + mp * 16 + r4;
                #pragma unroll
                for (int nh = 0; nh < 2; ++nh)
                    #pragma unroll
                    for (int np = 0; np < 2; ++np) {
                        long gcol = (long)bn * 256 + nh * 128 + wn * 32 + np * 16 + cl;
                        #pragma unroll
                        for (int r = 0; r < 4; ++r) {
                            float v = acc[mh][nh][mp][np][r] + bv[nh][np];
                            if (RELU) v = fmaxf(v, 0.f);
                            ((float*)Cout)[(grow + r) * (long)N + gcol] = v;
                        }
                    }
            }
    }
#undef GLA_
#undef GLB_
#undef READA_
#undef READB_
#undef QUAD
#undef VMW
#undef KTILE
}

// ---------- fused: latent(16) -> quantum circuit -> D1 ----------
__global__ __launch_bounds__(256) void latq_d1(
    const unsigned short* __restrict__ h2,  // B x 1024 bf16
    const float* __restrict__ We3,          // 256 x 1024 (rows 0..15 used)
    const float* __restrict__ be3,          // 256
    const float* __restrict__ P,            // 2 x 16 x 3
    const float* __restrict__ Wd1,          // 1024 x 16
    const float* __restrict__ bd1,          // 1024
    unsigned short* __restrict__ h3)        // B x 1024 bf16
{
    __shared__ float zsh[4][16];
    const int lane = threadIdx.x & 63;
    const int wv   = threadIdx.x >> 6;
    const long row = (long)blockIdx.x * 4 + wv;

    float hreg[16];
    const unsigned short* hr = h2 + row * 1024;
    #pragma unroll
    for (int j = 0; j < 16; ++j) hreg[j] = bf2f(hr[lane + 64 * j]);

    float myth = 0.f;
    #pragma unroll
    for (int q = 0; q < 16; ++q) {
        const float* wq = We3 + q * 1024;
        float p = 0.f;
        #pragma unroll
        for (int j = 0; j < 16; ++j) p += hreg[j] * wq[lane + 64 * j];
        #pragma unroll
        for (int o = 32; o; o >>= 1) p += __shfl_xor(p, o, 64);
        if (lane == q) myth = p + be3[q];
    }

    if (lane < 16) {
        const int q = lane;
        float ar = cosf(0.5f * myth), ai = 0.f;
        float br = sinf(0.5f * myth), bi = 0.f;
        #pragma unroll
        for (int l = 0; l < 2; ++l) {
            const float* pp = P + (l * 16 + q) * 3;
            float t, c, s, ar2, ai2, br2, bi2;
            t = 0.5f * pp[0]; c = cosf(t); s = sinf(t);
            ar2 = c * ar + s * bi;  ai2 = c * ai - s * br;
            br2 = c * br + s * ai;  bi2 = c * bi - s * ar;
            ar = ar2; ai = ai2; br = br2; bi = bi2;
            t = 0.5f * pp[1]; c = cosf(t); s = sinf(t);
            ar2 = c * ar - s * br;  ai2 = c * ai - s * bi;
            br2 = s * ar + c * br;  bi2 = s * ai + c * bi;
            ar = ar2; ai = ai2; br = br2; bi = bi2;
            t = 0.5f * pp[2]; c = cosf(t); s = sinf(t);
            ar2 = ar * c + ai * s;  ai2 = ai * c - ar * s;
            br2 = br * c - bi * s;  bi2 = bi * c + br * s;
            ar = ar2; ai = ai2; br = br2; bi = bi2;
        }
        zsh[wv][q] = ar * ar + ai * ai - (br * br + bi * bi);
    }
    __syncthreads();

    float z[16];
    #pragma unroll
    for (int q = 0; q < 16; ++q) z[q] = zsh[wv][q];

    unsigned short* orow = h3 + row * 1024;
    #pragma unroll
    for (int i = 0; i < 16; ++i) {
        int j = lane + 64 * i;
        const float4* wrow = (const float4*)(Wd1 + j * 16);
        float acc = bd1[j];
        #pragma unroll
        for (int qq = 0; qq < 4; ++qq) {
            float4 w4 = wrow[qq];
            acc += z[qq * 4 + 0] * w4.x + z[qq * 4 + 1] * w4.y
                 + z[qq * 4 + 2] * w4.z + z[qq * 4 + 3] * w4.w;
        }
        orow[j] = f2bf(fmaxf(acc, 0.f));
    }
}

// ---------- host ----------
extern "C" void kernel_launch(void* const* d_in, const int* in_sizes, int n_in,
                              void* d_out, int out_size, void* d_ws, size_t ws_size,
                              hipStream_t stream) {
    const float* x   = (const float*)d_in[0];
    const float* We1 = (const float*)d_in[1];
    const float* be1 = (const float*)d_in[2];
    const float* We2 = (const float*)d_in[3];
    const float* be2 = (const float*)d_in[4];
    const float* We3 = (const float*)d_in[5];
    const float* be3 = (const float*)d_in[6];
    const float* P   = (const float*)d_in[7];
    const float* Wd1 = (const float*)d_in[8];
    const float* bd1 = (const float*)d_in[9];
    const float* Wd2 = (const float*)d_in[10];
    const float* bd2 = (const float*)d_in[11];
    const float* Wd3 = (const float*)d_in[12];
    const float* bd3 = (const float*)d_in[13];

    const int B = 8192, DIN = 4096, NH1 = 2048, NH2 = 1024;

    char* w = (char*)d_ws;
    unsigned short* x_bf   = (unsigned short*)(w);                    // 64MB
    unsigned short* h4     = x_bf;                                    // alias (x dead after G1)
    unsigned short* We1_bf = (unsigned short*)(w + 67108864L);        // 16MB
    unsigned short* We2_bf = (unsigned short*)(w + 83886080L);        // 4MB
    unsigned short* Wd2_bf = (unsigned short*)(w + 88080384L);        // 4MB
    unsigned short* Wd3_bf = (unsigned short*)(w + 92274688L);        // 16MB
    unsigned short* h1     = (unsigned short*)(w + 109051904L);       // 32MB
    unsigned short* h3     = h1;                                      // alias (h1 dead after G2)
    unsigned short* h2     = (unsigned short*)(w + 142606336L);       // 16MB

    Cast5 ca;
    ca.s0 = x;   ca.d0 = x_bf;   ca.n0 = (int)((long)B * DIN / 4);
    ca.s1 = We1; ca.d1 = We1_bf; ca.n1 = (int)((long)NH1 * DIN / 4);
    ca.s2 = We2; ca.d2 = We2_bf; ca.n2 = (int)((long)NH2 * NH1 / 4);
    ca.s3 = Wd2; ca.d3 = Wd2_bf; ca.n3 = (int)((long)NH1 * NH2 / 4);
    ca.s4 = Wd3; ca.d4 = Wd3_bf;
    ca.total = ca.n0 + ca.n1 + ca.n2 + ca.n3 + (int)((long)DIN * NH1 / 4);
    castall<<<2048, 256, 0, stream>>>(ca);

    // G1: h1 = relu(x @ We1^T + be1)   8192x2048 K=4096   (256x256)
    gemm8p<1, 1, 4><<<dim3(NH1 / 256, B / 256), 512, 0, stream>>>(x_bf, We1_bf, be1, h1, NH1, DIN, DIN >> 6);
    // G2: h2 = relu(h1 @ We2^T + be2)  8192x1024 K=2048   (128x256)
    gemm8p<1, 1, 2><<<dim3(NH2 / 256, B / 128), 512, 0, stream>>>(h1, We2_bf, be2, h2, NH2, NH1, NH1 >> 6);
    // latent -> quantum -> D1
    latq_d1<<<dim3(B / 4), 256, 0, stream>>>(h2, We3, be3, P, Wd1, bd1, h3);
    // D2: h4 = relu(h3 @ Wd2^T + bd2)  8192x2048 K=1024   (256x256)
    gemm8p<1, 1, 4><<<dim3(NH1 / 256, B / 256), 512, 0, stream>>>(h3, Wd2_bf, bd2, h4, NH1, NH2, NH2 >> 6);
    // D3: out = h4 @ Wd3^T + bd3       8192x4096 K=2048 -> f32
    gemm8p<0, 0, 4><<<dim3(DIN / 256, B / 256), 512, 0, stream>>>(h4, Wd3_bf, bd3, d_out, DIN, NH1, NH1 >> 6);
}

// Round 12
// 377.574 us; speedup vs baseline: 1.3323x; 1.0093x over previous
//
#include <hip/hip_runtime.h>

// ---------- types / helpers ----------
typedef __attribute__((ext_vector_type(8))) short bf16x8;  // 8 bf16 (4 VGPRs)
typedef __attribute__((ext_vector_type(4))) float f32x4;

__device__ __forceinline__ unsigned short f2bf(float f) {
    union { float f; unsigned int u; } v; v.f = f;
    unsigned int u = v.u;
    unsigned int r = (u + 0x7FFFu + ((u >> 16) & 1u)) >> 16;   // RNE
    return (unsigned short)r;
}
__device__ __forceinline__ float bf2f(unsigned short b) {
    union { unsigned int u; float f; } v; v.u = ((unsigned int)b) << 16;
    return v.f;
}

#define GL16(g, l)                                                             \
    __builtin_amdgcn_global_load_lds(                                          \
        (__attribute__((address_space(1))) void*)(void*)(g),                   \
        (__attribute__((address_space(3))) void*)(void*)(l), 16, 0, 0)

#define BAR()   __builtin_amdgcn_s_barrier()
#define LGKM0() asm volatile("s_waitcnt lgkmcnt(0)" ::: "memory")

// ---------- merged f32 -> bf16 casts (one launch, 5 segments) ----------
struct Cast5 {
    const float *s0, *s1, *s2, *s3, *s4;
    unsigned short *d0, *d1, *d2, *d3, *d4;
    int n0, n1, n2, n3, total;
};
__global__ void castall(Cast5 a) {
    int stride = gridDim.x * blockDim.x;
    for (int i = blockIdx.x * blockDim.x + threadIdx.x; i < a.total; i += stride) {
        int j = i; const float* s; unsigned short* d;
        if (j < a.n0) { s = a.s0; d = a.d0; }
        else { j -= a.n0;
            if (j < a.n1) { s = a.s1; d = a.d1; }
            else { j -= a.n1;
                if (j < a.n2) { s = a.s2; d = a.d2; }
                else { j -= a.n2;
                    if (j < a.n3) { s = a.s3; d = a.d3; }
                    else { j -= a.n3; s = a.s4; d = a.d4; } } } }
        float4 v = ((const float4*)s)[j];
        ushort4 o;
        o.x = f2bf(v.x); o.y = f2bf(v.y); o.z = f2bf(v.z); o.w = f2bf(v.w);
        ((ushort4*)d)[j] = o;
    }
}

// ---------- 8-phase (MP*64 x 256) NT GEMM, 2 barriers/K-tile ----------
// R10 base (381us) + (a) b1 read hoisted P2->P1 (reads 12/0/8/4); (b) bm-major
// grid (blockIdx.x = bm) for XCD-local A panels.
// REGISTER LIVENESS (R11 lesson): b0(t) is consumed at P1 AND P4 -> b0(t+1)
// read MUST stay after P4's QUAD. b1(t) last use is P3 -> P1 read of b1(t) is
// legal (b1(t-1) dead since (t-1).P3).
// Ledger (MP=4, 2-op stages; stages P1:A1(t+1) P2:B0(t+2) P3:A0(t+2)
// P4:B1(t+2); vmcnt(6) at P2/P4):
//  read a1(t),b1(t) @P1 <- staged (t-1).P1 / (t-2).P4; covered by (t-1).P4's
//                          VMW(6)+BAR (6 newer ops = B0,A0,B1 of t+1/t+2)
//  read a0(t+1) @P3     <- staged (t-1).P3; covered by t.P2's VMW(6)+BAR
//  read b0(t+1) @P4 post-QUAD <- staged (t-1).P2; covered by same VMW+BAR
// WAR: overwrites land >=1 VMW+BAR after all-wave lgkm-consumption.

template<int RELU, int OUT_BF16, int MP>
__global__ __launch_bounds__(512, 2) void gemm8p(
    const unsigned short* __restrict__ A,   // M x K bf16
    const unsigned short* __restrict__ Bm,  // N x K bf16
    const float* __restrict__ bias,         // N
    void* __restrict__ Cout,                // M x N
    int N, int K, int NT)
{
    constexpr int AHU  = MP * 2048;       // ushorts per A half (MP*32 rows x 64)
    constexpr int BOFF = MP * 8192;       // ushort offset of B region
    __shared__ __align__(16) unsigned short lds[MP * 8192 + 32768];

    const int tid  = threadIdx.x;
    const int lane = tid & 63;
    const int w    = tid >> 6;
    const int wm   = w >> 2;           // 0..1
    const int wn   = w & 3;            // 0..3
    const int bm   = blockIdx.x;       // bm-major dispatch (XCD locality)
    const int bn   = blockIdx.y;

    // ---- block panel bases (uniform -> SGPR) ----
    const unsigned short* gA = A  + (long)bm * (MP * 64) * K;
    const unsigned short* gB = Bm + (long)bn * 256 * K;

    // ---- staging: per-lane byte offset within a half-panel ----
    const int sr0 = tid >> 3;                                      // row 0..63
    const int so0 = (((tid & 7) * 16) ^ ((sr0 & 7) << 4)) >> 1;    // swizzled col (ushort)
    const int loff = (sr0 * K + so0) * 2;                          // bytes
    const int ch1  = K * 128;                                      // +64 rows, bytes
    const int lb0 = (w * 64) * 8;            // wave-uniform LDS chunk base (ushort idx)
    const int lb1 = (512 + w * 64) * 8;

    // ---- LDS read bases (per-lane VGPR, byte) ----
    const int cl  = lane & 15;
    const int g16 = (lane >> 4) * 16;
    const int sw  = (cl & 7) << 4;
    const int cK0 = (g16 ^ sw) >> 1;
    const int cK1 = ((64 + g16) ^ sw) >> 1;
    const int arb = wm * (MP * 16) + cl;
    const int brb = wn * 32 + cl;
    const int aIdx0 = (arb * 64 + cK0) * 2;
    const int aIdx1 = (arb * 64 + cK1) * 2;
    const int bIdx0 = (BOFF + brb * 64 + cK0) * 2;
    const int bIdx1 = (BOFF + brb * 64 + cK1) * 2;

    f32x4  acc[2][2][MP][2] = {};
    bf16x8 a0[MP][2], a1[MP][2], b0[2][2], b1[2][2];

#define GLA_(SP, DI) do {                                                      \
        GL16((const char*)(SP) + loff, &lds[0] + (DI) + lb0);                  \
        if constexpr (MP == 4) {                                               \
            GL16((const char*)(SP) + loff + ch1, &lds[0] + (DI) + lb1); }      \
    } while (0)
#define GLB_(SP, DI) do {                                                      \
        GL16((const char*)(SP) + loff, &lds[0] + (DI) + lb0);                  \
        GL16((const char*)(SP) + loff + ch1, &lds[0] + (DI) + lb1);            \
    } while (0)

#define READA_(AR, MH, PAR) do {                                               \
        _Pragma("unroll") for (int mp_ = 0; mp_ < MP; ++mp_) {                 \
            AR[mp_][0] = *(const bf16x8*)((const char*)lds + aIdx0 +           \
                         (((PAR)*2+(MH))*AHU*2 + mp_*2048));                   \
            AR[mp_][1] = *(const bf16x8*)((const char*)lds + aIdx1 +           \
                         (((PAR)*2+(MH))*AHU*2 + mp_*2048));                   \
        } } while (0)
#define READB_(BR, NH, PAR) do {                                               \
        _Pragma("unroll") for (int np_ = 0; np_ < 2; ++np_) {                  \
            BR[np_][0] = *(const bf16x8*)((const char*)lds + bIdx0 +           \
                         (((PAR)*2+(NH))*16384 + np_*2048));                   \
            BR[np_][1] = *(const bf16x8*)((const char*)lds + bIdx1 +           \
                         (((PAR)*2+(NH))*16384 + np_*2048));                   \
        } } while (0)
#define QUAD(mh, nh, AR, BR) do {                                              \
        __builtin_amdgcn_s_setprio(1);                                         \
        _Pragma("unroll") for (int kk_ = 0; kk_ < 2; ++kk_)                    \
        _Pragma("unroll") for (int mp_ = 0; mp_ < MP; ++mp_)                   \
        _Pragma("unroll") for (int np_ = 0; np_ < 2; ++np_)                    \
            acc[mh][nh][mp_][np_] = __builtin_amdgcn_mfma_f32_16x16x32_bf16(   \
                AR[mp_][kk_], BR[np_][kk_], acc[mh][nh][mp_][np_], 0, 0, 0);   \
        __builtin_amdgcn_s_setprio(0);                                         \
    } while (0)
#define VMW() do {                                                             \
        if constexpr (MP == 4) asm volatile("s_waitcnt vmcnt(6)" ::: "memory");\
        else                   asm volatile("s_waitcnt vmcnt(5)" ::: "memory");\
    } while (0)

    // ---- prologue: tile0 {B0,A0,B1,A1} + tile1 {B0,A0,B1} (this op order!) ----
    GLB_(gB,                      BOFF + 0);
    GLA_(gA,                      0);
    GLB_(gB + (long)128 * K,      BOFF + 8192);
    GLA_(gA + (long)(MP*32) * K,  AHU);
    GLB_(gB + 64,                 BOFF + 2*8192);
    GLA_(gA + 64,                 2*AHU);
    GLB_(gB + (long)128 * K + 64, BOFF + 3*8192);
    VMW();
    BAR();
    READA_(a0, 0, 0);
    READB_(b0, 0, 0);

    // ---- running scalar column pointers ----
    const unsigned short* sA1 = gA + (long)(MP*32) * K + 64;   // col 1
    const unsigned short* sA0 = gA + 128;                      // col 2
    const unsigned short* sB0 = gB + 128;                      // col 2
    const unsigned short* sB1 = gB + (long)128 * K + 128;      // col 2

#define KTILE(T, PAR) do {                                                     \
        const int adv1_ = ((T) + 2 < NT) ? 64 : 0;                             \
        const int adv2_ = ((T) + 3 < NT) ? 64 : 0;                             \
        /* P1 (no barrier): read a1(t), b1(t) */                               \
        READA_(a1, 1, PAR);                                                    \
        READB_(b1, 1, PAR);                                                    \
        GLA_(sA1, (((PAR)^1)*2+1)*AHU); sA1 += adv1_;                          \
        QUAD(0, 0, a0, b0);                                                    \
        /* P2 */                                                               \
        GLB_(sB0, BOFF + (PAR)*2*8192); sB0 += adv2_;                          \
        VMW();                                                                 \
        BAR();                                                                 \
        QUAD(0, 1, a0, b1);                                                    \
        /* P3 (no barrier): read a0(t+1) */                                    \
        READA_(a0, 0, (PAR)^1);                                                \
        GLA_(sA0, (PAR)*2*AHU); sA0 += adv2_;                                  \
        QUAD(1, 1, a1, b1);                                                    \
        /* P4 */                                                               \
        GLB_(sB1, BOFF + ((PAR)*2+1)*8192); sB1 += adv2_;                      \
        VMW();                                                                 \
        BAR();                                                                 \
        QUAD(1, 0, a1, b0);                                                    \
        READB_(b0, 0, (PAR)^1);   /* b0(t+1): AFTER QUAD(1,0) (liveness!) */   \
    } while (0)

    for (int t = 0; t < NT; t += 2) {
        KTILE(t, 0);
        KTILE(t + 1, 1);
    }

    // drain clamped wrap-stagings before LDS reuse / kernel end
    asm volatile("s_waitcnt vmcnt(0)" ::: "memory");
    BAR();

    // ---- epilogue ----
    const int r4 = (lane >> 4) * 4;
    float bv[2][2];
    #pragma unroll
    for (int nh = 0; nh < 2; ++nh)
        #pragma unroll
        for (int np = 0; np < 2; ++np)
            bv[nh][np] = bias[(long)bn * 256 + nh * 128 + wn * 32 + np * 16 + cl];

    if (OUT_BF16) {
        unsigned short* epi = lds;
        #pragma unroll
        for (int h = 0; h < 2; ++h) {
            if (h) { LGKM0(); BAR(); }
            #pragma unroll
            for (int mp = 0; mp < MP; ++mp)
                #pragma unroll
                for (int nh = 0; nh < 2; ++nh)
                    #pragma unroll
                    for (int np = 0; np < 2; ++np)
                        #pragma unroll
                        for (int r = 0; r < 4; ++r) {
                            float v = acc[h][nh][mp][np][r] + bv[nh][np];
                            if (RELU) v = fmaxf(v, 0.f);
                            int lrow = wm * (MP * 16) + mp * 16 + r4 + r;
                            int lcol = nh * 128 + wn * 32 + np * 16 + cl;
                            epi[lrow * 264 + lcol] = f2bf(v);
                        }
            LGKM0();
            BAR();
            long rowg0 = (long)bm * (MP * 64) + h * (MP * 32);
            #pragma unroll
            for (int i = 0; i < 2 * MP; ++i) {
                int row = (tid >> 5) + i * 16;
                int cc  = (tid & 31) * 8;
                bf16x8 v8 = *(const bf16x8*)&epi[row * 264 + cc];
                *(bf16x8*)((unsigned short*)Cout + (rowg0 + row) * (long)N + (long)bn * 256 + cc) = v8;
            }
        }
    } else {
        #pragma unroll
        for (int mh = 0; mh < 2; ++mh)
            #pragma unroll
            for (int mp = 0; mp < MP; ++mp) {
                long grow = (long)bm * (MP * 64) + mh * (MP * 32) + wm * (MP * 16) + mp * 16 + r4;
                #pragma unroll
                for (int nh = 0; nh < 2; ++nh)
                    #pragma unroll
                    for (int np = 0; np < 2; ++np) {
                        long gcol = (long)bn * 256 + nh * 128 + wn * 32 + np * 16 + cl;
                        #pragma unroll
                        for (int r = 0; r < 4; ++r) {
                            float v = acc[mh][nh][mp][np][r] + bv[nh][np];
                            if (RELU) v = fmaxf(v, 0.f);
                            ((float*)Cout)[(grow + r) * (long)N + gcol] = v;
                        }
                    }
            }
    }
#undef GLA_
#undef GLB_
#undef READA_
#undef READB_
#undef QUAD
#undef VMW
#undef KTILE
}

// ---------- fused: latent(16) -> quantum circuit -> D1 ----------
__global__ __launch_bounds__(256) void latq_d1(
    const unsigned short* __restrict__ h2,  // B x 1024 bf16
    const float* __restrict__ We3,          // 256 x 1024 (rows 0..15 used)
    const float* __restrict__ be3,          // 256
    const float* __restrict__ P,            // 2 x 16 x 3
    const float* __restrict__ Wd1,          // 1024 x 16
    const float* __restrict__ bd1,          // 1024
    unsigned short* __restrict__ h3)        // B x 1024 bf16
{
    __shared__ float zsh[4][16];
    const int lane = threadIdx.x & 63;
    const int wv   = threadIdx.x >> 6;
    const long row = (long)blockIdx.x * 4 + wv;

    float hreg[16];
    const unsigned short* hr = h2 + row * 1024;
    #pragma unroll
    for (int j = 0; j < 16; ++j) hreg[j] = bf2f(hr[lane + 64 * j]);

    float myth = 0.f;
    #pragma unroll
    for (int q = 0; q < 16; ++q) {
        const float* wq = We3 + q * 1024;
        float p = 0.f;
        #pragma unroll
        for (int j = 0; j < 16; ++j) p += hreg[j] * wq[lane + 64 * j];
        #pragma unroll
        for (int o = 32; o; o >>= 1) p += __shfl_xor(p, o, 64);
        if (lane == q) myth = p + be3[q];
    }

    if (lane < 16) {
        const int q = lane;
        float ar = cosf(0.5f * myth), ai = 0.f;
        float br = sinf(0.5f * myth), bi = 0.f;
        #pragma unroll
        for (int l = 0; l < 2; ++l) {
            const float* pp = P + (l * 16 + q) * 3;
            float t, c, s, ar2, ai2, br2, bi2;
            t = 0.5f * pp[0]; c = cosf(t); s = sinf(t);
            ar2 = c * ar + s * bi;  ai2 = c * ai - s * br;
            br2 = c * br + s * ai;  bi2 = c * bi - s * ar;
            ar = ar2; ai = ai2; br = br2; bi = bi2;
            t = 0.5f * pp[1]; c = cosf(t); s = sinf(t);
            ar2 = c * ar - s * br;  ai2 = c * ai - s * bi;
            br2 = s * ar + c * br;  bi2 = s * ai + c * bi;
            ar = ar2; ai = ai2; br = br2; bi = bi2;
            t = 0.5f * pp[2]; c = cosf(t); s = sinf(t);
            ar2 = ar * c + ai * s;  ai2 = ai * c - ar * s;
            br2 = br * c - bi * s;  bi2 = bi * c + br * s;
            ar = ar2; ai = ai2; br = br2; bi = bi2;
        }
        zsh[wv][q] = ar * ar + ai * ai - (br * br + bi * bi);
    }
    __syncthreads();

    float z[16];
    #pragma unroll
    for (int q = 0; q < 16; ++q) z[q] = zsh[wv][q];

    unsigned short* orow = h3 + row * 1024;
    #pragma unroll
    for (int i = 0; i < 16; ++i) {
        int j = lane + 64 * i;
        const float4* wrow = (const float4*)(Wd1 + j * 16);
        float acc = bd1[j];
        #pragma unroll
        for (int qq = 0; qq < 4; ++qq) {
            float4 w4 = wrow[qq];
            acc += z[qq * 4 + 0] * w4.x + z[qq * 4 + 1] * w4.y
                 + z[qq * 4 + 2] * w4.z + z[qq * 4 + 3] * w4.w;
        }
        orow[j] = f2bf(fmaxf(acc, 0.f));
    }
}

// ---------- host ----------
extern "C" void kernel_launch(void* const* d_in, const int* in_sizes, int n_in,
                              void* d_out, int out_size, void* d_ws, size_t ws_size,
                              hipStream_t stream) {
    const float* x   = (const float*)d_in[0];
    const float* We1 = (const float*)d_in[1];
    const float* be1 = (const float*)d_in[2];
    const float* We2 = (const float*)d_in[3];
    const float* be2 = (const float*)d_in[4];
    const float* We3 = (const float*)d_in[5];
    const float* be3 = (const float*)d_in[6];
    const float* P   = (const float*)d_in[7];
    const float* Wd1 = (const float*)d_in[8];
    const float* bd1 = (const float*)d_in[9];
    const float* Wd2 = (const float*)d_in[10];
    const float* bd2 = (const float*)d_in[11];
    const float* Wd3 = (const float*)d_in[12];
    const float* bd3 = (const float*)d_in[13];

    const int B = 8192, DIN = 4096, NH1 = 2048, NH2 = 1024;

    char* w = (char*)d_ws;
    unsigned short* x_bf   = (unsigned short*)(w);                    // 64MB
    unsigned short* h4     = x_bf;                                    // alias (x dead after G1)
    unsigned short* We1_bf = (unsigned short*)(w + 67108864L);        // 16MB
    unsigned short* We2_bf = (unsigned short*)(w + 83886080L);        // 4MB
    unsigned short* Wd2_bf = (unsigned short*)(w + 88080384L);        // 4MB
    unsigned short* Wd3_bf = (unsigned short*)(w + 92274688L);        // 16MB
    unsigned short* h1     = (unsigned short*)(w + 109051904L);       // 32MB
    unsigned short* h3     = h1;                                      // alias (h1 dead after G2)
    unsigned short* h2     = (unsigned short*)(w + 142606336L);       // 16MB

    Cast5 ca;
    ca.s0 = x;   ca.d0 = x_bf;   ca.n0 = (int)((long)B * DIN / 4);
    ca.s1 = We1; ca.d1 = We1_bf; ca.n1 = (int)((long)NH1 * DIN / 4);
    ca.s2 = We2; ca.d2 = We2_bf; ca.n2 = (int)((long)NH2 * NH1 / 4);
    ca.s3 = Wd2; ca.d3 = Wd2_bf; ca.n3 = (int)((long)NH1 * NH2 / 4);
    ca.s4 = Wd3; ca.d4 = Wd3_bf;
    ca.total = ca.n0 + ca.n1 + ca.n2 + ca.n3 + (int)((long)DIN * NH1 / 4);
    castall<<<2048, 256, 0, stream>>>(ca);

    // bm-major grids: blockIdx.x = bm (XCD locality on A panels)
    // G1: h1 = relu(x @ We1^T + be1)   8192x2048 K=4096   (256x256)
    gemm8p<1, 1, 4><<<dim3(B / 256, NH1 / 256), 512, 0, stream>>>(x_bf, We1_bf, be1, h1, NH1, DIN, DIN >> 6);
    // G2: h2 = relu(h1 @ We2^T + be2)  8192x1024 K=2048   (128x256)
    gemm8p<1, 1, 2><<<dim3(B / 128, NH2 / 256), 512, 0, stream>>>(h1, We2_bf, be2, h2, NH2, NH1, NH1 >> 6);
    // latent -> quantum -> D1
    latq_d1<<<dim3(B / 4), 256, 0, stream>>>(h2, We3, be3, P, Wd1, bd1, h3);
    // D2: h4 = relu(h3 @ Wd2^T + bd2)  8192x2048 K=1024   (256x256)
    gemm8p<1, 1, 4><<<dim3(B / 256, NH1 / 256), 512, 0, stream>>>(h3, Wd2_bf, bd2, h4, NH1, NH2, NH2 >> 6);
    // D3: out = h4 @ Wd3^T + bd3       8192x4096 K=2048 -> f32
    gemm8p<0, 0, 4><<<dim3(B / 256, DIN / 256), 512, 0, stream>>>(h4, Wd3_bf, bd3, d_out, DIN, NH1, NH1 >> 6);
}